// Round 2
// baseline (2050.972 us; speedup 1.0000x reference)
//
#include <hip/hip_runtime.h>

// ---------------------------------------------------------------------------
// Attention block, fp32 in/out, bf16 MFMA internal:
//   cvt x,wq,wk,wv,wo -> bf16
//   Q = x@wq^T+bq ; K = x@wk^T+bk ; V = x@wv^T+bv   (MFMA GEMMs, bf16 out)
//   RoPE(Q [fused *1/sqrt(128)]), RoPE(K)
//   flash attention (causal, GQA 4:1), MFMA 16x16x32
//   out = attn@wo^T+bo  (fp32 out)
// Workspace (bf16 elems): xb 16.7M (reused as At), wqb 16.7M (reused as wob),
// wkb 4.2M, wvb 4.2M, Qb 16.7M, Kb 4.2M, Vt 4.2M  = 128 MiB
// ---------------------------------------------------------------------------

using bf16x8 = __attribute__((ext_vector_type(8))) short;
using f32x4  = __attribute__((ext_vector_type(4))) float;
using u16x4  = __attribute__((ext_vector_type(4))) unsigned short;
using u16x8  = __attribute__((ext_vector_type(8))) unsigned short;

__device__ __forceinline__ float bf2f(unsigned short h) {
    unsigned int u = ((unsigned int)h) << 16;
    return __builtin_bit_cast(float, u);
}
__device__ __forceinline__ unsigned short f2bf(float f) {
    unsigned int u = __builtin_bit_cast(unsigned int, f);
    u += 0x7FFFu + ((u >> 16) & 1u);   // round-to-nearest-even
    return (unsigned short)(u >> 16);
}
__device__ __forceinline__ f32x4 mfma16(bf16x8 a, bf16x8 b, f32x4 c) {
    return __builtin_amdgcn_mfma_f32_16x16x32_bf16(a, b, c, 0, 0, 0);
}

// ---------------------------------------------------------------------------
// fp32 -> bf16 conversion, 8 elems/thread
// ---------------------------------------------------------------------------
__global__ __launch_bounds__(256) void cvt_kernel(
    const float* __restrict__ src, unsigned short* __restrict__ dst, int n)
{
    const int i = (blockIdx.x * 256 + threadIdx.x) * 8;
    if (i >= n) return;
    float4 a = *(const float4*)(src + i);
    float4 b = *(const float4*)(src + i + 4);
    u16x8 o;
    o[0] = f2bf(a.x); o[1] = f2bf(a.y); o[2] = f2bf(a.z); o[3] = f2bf(a.w);
    o[4] = f2bf(b.x); o[5] = f2bf(b.y); o[6] = f2bf(b.z); o[7] = f2bf(b.w);
    *(u16x8*)(dst + i) = o;
}

// ---------------------------------------------------------------------------
// GEMM: C[M,N] = A[M,K] @ W[N,K]^T + bias[N]  (bf16 in, fp32 accum)
// Block 256 thr = 4 waves as 2x2; block tile 128x128; wave tile 64x64.
// FINAL=false: bf16 out (TRANSV optionally transposes for the V buffer).
// FINAL=true : fp32 out.
// ---------------------------------------------------------------------------
template<bool TRANSV, bool FINAL>
__global__ __launch_bounds__(256) void gemm_bias(
    const unsigned short* __restrict__ A, const unsigned short* __restrict__ W,
    const float* __restrict__ bias, void* __restrict__ Cv,
    int M, int N, int K)
{
    const int lane = threadIdx.x & 63;
    const int wv   = threadIdx.x >> 6;
    const int ln   = lane & 15, quad = lane >> 4;
    const int m0 = blockIdx.y * 128 + (wv >> 1) * 64;
    const int n0 = blockIdx.x * 128 + (wv & 1) * 64;

    const unsigned short* ap[4];
    const unsigned short* bp[4];
#pragma unroll
    for (int i = 0; i < 4; ++i) ap[i] = A + (size_t)(m0 + i * 16 + ln) * K + quad * 8;
#pragma unroll
    for (int j = 0; j < 4; ++j) bp[j] = W + (size_t)(n0 + j * 16 + ln) * K + quad * 8;

    f32x4 acc[4][4];
#pragma unroll
    for (int i = 0; i < 4; ++i)
#pragma unroll
        for (int j = 0; j < 4; ++j) acc[i][j] = f32x4{0.f, 0.f, 0.f, 0.f};

    for (int k = 0; k < K; k += 32) {
        bf16x8 af[4], bfr[4];
#pragma unroll
        for (int i = 0; i < 4; ++i) { af[i]  = *(const bf16x8*)ap[i]; ap[i] += 32; }
#pragma unroll
        for (int j = 0; j < 4; ++j) { bfr[j] = *(const bf16x8*)bp[j]; bp[j] += 32; }
#pragma unroll
        for (int i = 0; i < 4; ++i)
#pragma unroll
            for (int j = 0; j < 4; ++j)
                acc[i][j] = mfma16(af[i], bfr[j], acc[i][j]);
    }

#pragma unroll
    for (int j = 0; j < 4; ++j) {
        const int col = n0 + j * 16 + ln;
        const float bv = bias[col];
#pragma unroll
        for (int i = 0; i < 4; ++i) {
            const int rowb = m0 + i * 16 + quad * 4;   // 4 consecutive rows
            if (FINAL) {
                float* C = (float*)Cv;
#pragma unroll
                for (int r = 0; r < 4; ++r)
                    C[(size_t)(rowb + r) * N + col] = acc[i][j][r] + bv;
            } else if (!TRANSV) {
                unsigned short* C = (unsigned short*)Cv;
#pragma unroll
                for (int r = 0; r < 4; ++r)
                    C[(size_t)(rowb + r) * N + col] = f2bf(acc[i][j][r] + bv);
            } else {
                // V: (b,s,g,d) -> (b,g,d,s); rows are s (4 consecutive) -> 8B store
                unsigned short* C = (unsigned short*)Cv;
                const int g = col >> 7, d = col & 127;
                const int bb = rowb >> 11, s = rowb & 2047;
                u16x4 pk;
#pragma unroll
                for (int r = 0; r < 4; ++r) pk[r] = f2bf(acc[i][j][r] + bv);
                *(u16x4*)(C + (((size_t)(bb * 8 + g) * 128 + d) * 2048 + s)) = pk;
            }
        }
    }
}

// ---------------------------------------------------------------------------
// RoPE in-place on Q (with 1/sqrt(128) score scale fused) and K (bf16).
// freqs are fp32. One thread per (even,odd) pair.
// ---------------------------------------------------------------------------
__global__ __launch_bounds__(256) void rope_kernel(
    unsigned short* __restrict__ Q, unsigned short* __restrict__ Kb,
    const float* __restrict__ fc, const float* __restrict__ fs)
{
    const int idx = blockIdx.x * 256 + threadIdx.x;
    const int NQP = 2 * 2048 * 32 * 64;   // 8,388,608 Q pairs
    const int NKP = 2 * 2048 * 8 * 64;    // 2,097,152 K pairs
    unsigned short* t; int s, i; float scale;
    if (idx < NQP) {
        i = idx & 63; const int bsh = idx >> 6;
        s = (bsh >> 5) & 2047;                  // (b,s,h): 32 heads
        t = Q + ((size_t)bsh << 7) + 2 * i;
        scale = 0.08838834764831845f;           // 1/sqrt(128)
    } else {
        const int p = idx - NQP;
        if (p >= NKP) return;
        i = p & 63; const int bsh = p >> 6;
        s = (bsh >> 3) & 2047;                  // 8 kv heads
        t = Kb + ((size_t)bsh << 7) + 2 * i;
        scale = 1.0f;
    }
    const float c = fc[s * 64 + i], sn = fs[s * 64 + i];
    const float a = bf2f(t[0]), b = bf2f(t[1]);
    t[0] = f2bf((a * c - b * sn) * scale);
    t[1] = f2bf((a * sn + b * c) * scale);
}

// ---------------------------------------------------------------------------
// Flash attention, causal, GQA. One wave per 16 Q-rows per head.
// Q (b,s,32,128) pre-scaled; K (b,s,8,128); Vt (b,8,128,2048); O (b,s,32,128).
// ---------------------------------------------------------------------------
__global__ __launch_bounds__(64) void attn_kernel(
    const unsigned short* __restrict__ Q, const unsigned short* __restrict__ K,
    const unsigned short* __restrict__ Vt, unsigned short* __restrict__ O)
{
    __shared__ __align__(16) unsigned short p_s[16 * 32];
    const int lane = threadIdx.x;
    const int ln = lane & 15, quad = lane >> 4;
    const int q0 = blockIdx.x * 16;
    const int h = blockIdx.y, b = blockIdx.z, g = h >> 2;

    bf16x8 qf[4];   // A frags: m=ln -> q row q0+ln, k=d=d4*32+quad*8+j
    const unsigned short* qrow =
        Q + ((size_t)((b * 2048 + q0 + ln) * 32 + h)) * 128 + quad * 8;
#pragma unroll
    for (int d4 = 0; d4 < 4; ++d4) qf[d4] = *(const bf16x8*)(qrow + d4 * 32);

    f32x4 oacc[8];
#pragma unroll
    for (int t = 0; t < 8; ++t) oacc[t] = f32x4{0.f, 0.f, 0.f, 0.f};
    float mi[4] = {-INFINITY, -INFINITY, -INFINITY, -INFINITY};
    float li[4] = {0.f, 0.f, 0.f, 0.f};

    const unsigned short* kbase = K + (size_t)b * 2048 * 1024 + g * 128 + quad * 8;
    const unsigned short* vbase = Vt + (size_t)(b * 8 + g) * 128 * 2048 + quad * 8;

    const int nk = (q0 + 47) >> 5;   // k-tiles covering k <= q0+15
    for (int kt = 0; kt < nk; ++kt) {
        const int k0 = kt * 32;
        f32x4 sc[2];
#pragma unroll
        for (int c = 0; c < 2; ++c) {
            const unsigned short* kr = kbase + (size_t)(k0 + c * 16 + ln) * 1024;
            f32x4 a = f32x4{0.f, 0.f, 0.f, 0.f};
#pragma unroll
            for (int d4 = 0; d4 < 4; ++d4) {
                bf16x8 kf = *(const bf16x8*)(kr + d4 * 32);
                a = mfma16(qf[d4], kf, a);
            }
            sc[c] = a;   // D: row(q)=q0+quad*4+r, col(k)=k0+c*16+ln
        }
        float alpha[4];
#pragma unroll
        for (int r = 0; r < 4; ++r) {
            const int qg = q0 + quad * 4 + r;
            float s0 = (k0 + ln <= qg)      ? sc[0][r] : -INFINITY;
            float s1 = (k0 + 16 + ln <= qg) ? sc[1][r] : -INFINITY;
            float mx = fmaxf(s0, s1);
#pragma unroll
            for (int off = 1; off < 16; off <<= 1) mx = fmaxf(mx, __shfl_xor(mx, off));
            const float mn = fmaxf(mi[r], mx);
            alpha[r] = __expf(mi[r] - mn);
            mi[r] = mn;
            const float p0 = __expf(s0 - mn);
            const float p1 = __expf(s1 - mn);
            float rs = p0 + p1;
#pragma unroll
            for (int off = 1; off < 16; off <<= 1) rs += __shfl_xor(rs, off);
            li[r] = li[r] * alpha[r] + rs;
            sc[0][r] = p0; sc[1][r] = p1;
        }
        // P: C-layout -> LDS (q,k) -> A-layout frag
#pragma unroll
        for (int c = 0; c < 2; ++c)
#pragma unroll
            for (int r = 0; r < 4; ++r)
                p_s[(quad * 4 + r) * 32 + c * 16 + ln] = f2bf(sc[c][r]);
        __asm__ volatile("s_waitcnt lgkmcnt(0)" ::: "memory");
        bf16x8 pf = *(const bf16x8*)(p_s + ln * 32 + quad * 8);
#pragma unroll
        for (int t = 0; t < 8; ++t) {
            f32x4 o = oacc[t];
            o[0] *= alpha[0]; o[1] *= alpha[1]; o[2] *= alpha[2]; o[3] *= alpha[3];
            bf16x8 vf = *(const bf16x8*)(vbase + (size_t)(t * 16 + ln) * 2048 + k0);
            oacc[t] = mfma16(pf, vf, o);
        }
        __asm__ volatile("s_waitcnt lgkmcnt(0)" ::: "memory");
    }
    float inv[4];
#pragma unroll
    for (int r = 0; r < 4; ++r) inv[r] = 1.0f / li[r];
    unsigned short* ob = O + ((size_t)((b * 2048 + q0 + quad * 4) * 32 + h)) * 128;
#pragma unroll
    for (int t = 0; t < 8; ++t)
#pragma unroll
        for (int r = 0; r < 4; ++r)
            ob[(size_t)r * 32 * 128 + t * 16 + ln] = f2bf(oacc[t][r] * inv[r]);
}

// ---------------------------------------------------------------------------
extern "C" void kernel_launch(void* const* d_in, const int* in_sizes, int n_in,
                              void* d_out, int out_size, void* d_ws, size_t ws_size,
                              hipStream_t stream)
{
    const float* x  = (const float*)d_in[0];
    const float* fc = (const float*)d_in[1];
    const float* fs = (const float*)d_in[2];
    // d_in[3] = mask (unused; causal structure is known)
    const float* wq = (const float*)d_in[4];
    const float* bq = (const float*)d_in[5];
    const float* wk = (const float*)d_in[6];
    const float* bk = (const float*)d_in[7];
    const float* wv = (const float*)d_in[8];
    const float* bv = (const float*)d_in[9];
    const float* wo = (const float*)d_in[10];
    const float* bo = (const float*)d_in[11];

    unsigned short* wsp = (unsigned short*)d_ws;
    unsigned short* xb  = wsp;               // 16,777,216 (b,s,D) — reused as At
    unsigned short* wqb = xb  + 16777216;    // 16,777,216 — reused as wob
    unsigned short* wkb = wqb + 16777216;    //  4,194,304
    unsigned short* wvb = wkb + 4194304;     //  4,194,304
    unsigned short* Qb  = wvb + 4194304;     // 16,777,216 (b,s,32,128)
    unsigned short* Kb  = Qb  + 16777216;    //  4,194,304 (b,s,8,128)
    unsigned short* Vt  = Kb  + 4194304;     //  4,194,304 (b,8,128,s)

    // fp32 -> bf16
    cvt_kernel<<<8192, 256, 0, stream>>>(x,  xb,  16777216);
    cvt_kernel<<<8192, 256, 0, stream>>>(wq, wqb, 16777216);
    cvt_kernel<<<2048, 256, 0, stream>>>(wk, wkb, 4194304);
    cvt_kernel<<<2048, 256, 0, stream>>>(wv, wvb, 4194304);

    gemm_bias<false, false><<<dim3(32, 32), 256, 0, stream>>>(xb, wqb, bq, Qb, 4096, 4096, 4096);
    gemm_bias<false, false><<<dim3(8, 32),  256, 0, stream>>>(xb, wkb, bk, Kb, 4096, 1024, 4096);
    gemm_bias<true,  false><<<dim3(8, 32),  256, 0, stream>>>(xb, wvb, bv, Vt, 4096, 1024, 4096);

    // wqb free now -> reuse for wo
    cvt_kernel<<<8192, 256, 0, stream>>>(wo, wqb, 16777216);

    rope_kernel<<<40960, 256, 0, stream>>>(Qb, Kb, fc, fs);
    attn_kernel<<<dim3(128, 32, 2), 64, 0, stream>>>(Qb, Kb, Vt, xb);  // At = xb slot

    gemm_bias<false, true><<<dim3(32, 32), 256, 0, stream>>>(xb, wqb, bo,
                                                             d_out, 4096, 4096, 4096);
}